// Round 6
// baseline (412.471 us; speedup 1.0000x reference)
//
#include <hip/hip_runtime.h>

// FrozenHopfield: obs-mean -> random projection -> cosine-sim attention over
// vocab embeddings -> softmax(beta*sims) @ word_embs.
//
// B=256, C=3, HW=7056, HID=768, VOCAB=50257. Two big GEMMs in bf16 MFMA
// 16x16x32, fp32 accumulate. Logits bounded in [-8,8] so softmax needs no
// max subtraction: E=exp(logit), state=(E@W)/rowsum(E).
//
// R2: packed stores only (scattered shorts = 37x write amplification).
// R3: partial-coverage LDS store phases are silent poison; annotate coverage.
// R4: k_qgemm K-split 17 ways (was latency-bound at 48 blocks).
// R5/R6: k_wprep micro-fixes = zero delta; cost was structural.
// R7 (win, 449->415): WbT eliminated; gemm2 transposes its A-tile during LDS
// staging from row-major Wb.
// R8 (regression, 415->467): gemm2 merged tile -> 1 block/CU (6% occupancy),
// latency-serialized. Concurrency, not bytes, was the constraint. Reverted.
// R9 (win, 467->406): reg-prefetch pipeline in both GEMM k-loops (next
// k-step's loads issue under the MFMA cluster).
// R10: k_wprep DELETED. gemm1 reads W fp32 directly, converts in-register
// during B-staging, accumulates row norms in-block (inv_l[128] LDS; global
// inv_en buffer gone), and m-block 0 streams the bf16 tile out to Wb for
// gemm2. One full pass over W (154MB R + 77MB W) removed from the pipeline.

#define VOCAB 50257
#define VPAD  50304   // 393*128
#define HID   768
#define BATCH 256
#define IN    7056
#define INPAD 7072    // 221*32 = 17*416
#define NPAIR (INPAD / 2)   // 3536
#define SPLITS 32
#define CHUNK 1600    // gemm2 k-elems per split (1600*32 = 51200 >= VPAD)
#define QSPLITS 17
#define QCHUNK 416    // 13 iters of 32

typedef __attribute__((ext_vector_type(8))) __bf16 bf16x8;
typedef __attribute__((ext_vector_type(4))) float f32x4;

__device__ inline unsigned short f2bf(float f) {
  union { float f; unsigned u; } v; v.f = f;
  unsigned r = v.u + 0x7fffu + ((v.u >> 16) & 1u);   // RNE
  return (unsigned short)(r >> 16);
}
__device__ inline unsigned pack2(float lo, float hi) {
  return (unsigned)f2bf(lo) | ((unsigned)f2bf(hi) << 16);
}

// obsb[b][i] = bf16(mean_c obs[b][c][i]), zero pad cols; packed uint stores
__global__ __launch_bounds__(256) void k_obs(const float* __restrict__ obs,
                                             unsigned* __restrict__ obsb) {
  int b = blockIdx.x, t = threadIdx.x;
  const size_t base = (size_t)b * 3 * IN;
  for (int p = t; p < NPAIR; p += 256) {
    float x = 0.f, y = 0.f;
    if (2 * p < IN) {   // IN even: pair never straddles the boundary
      float2 a0 = *(const float2*)&obs[base + 2 * p];
      float2 a1 = *(const float2*)&obs[base + IN + 2 * p];
      float2 a2 = *(const float2*)&obs[base + 2 * IN + 2 * p];
      x = (a0.x + a1.x + a2.x) * (1.f / 3.f);
      y = (a0.y + a1.y + a2.y) * (1.f / 3.f);
    }
    obsb[b * NPAIR + p] = pack2(x, y);
  }
}

__global__ __launch_bounds__(256) void k_proj(const float* __restrict__ proj,
                                              unsigned* __restrict__ projb) {
  int h = blockIdx.x, t = threadIdx.x;
  for (int p = t; p < NPAIR; p += 256) {
    float x = 0.f, y = 0.f;
    if (2 * p < IN) {
      float2 xy = *(const float2*)&proj[(size_t)h * IN + 2 * p];
      x = xy.x; y = xy.y;
    }
    projb[h * NPAIR + p] = pack2(x, y);
  }
}

// ---------------- q projection GEMM (K-split): qp[s] = partial obs @ proj^T ----

__global__ __launch_bounds__(256) void k_qgemm(const unsigned short* __restrict__ A,  // obsb [256][INPAD]
                                               const unsigned short* __restrict__ Bm, // projb [768][INPAD]
                                               float* __restrict__ qp) {              // [QSPLITS][256][768]
  __shared__ unsigned short As[64][32];
  __shared__ unsigned short Bs[64][32];
  const int t = threadIdx.x;
  const int lane = t & 63, wave = t >> 6;
  const int wm = wave >> 1, wn = wave & 1;
  const int quad = lane >> 4, lo = lane & 15;
  const int m0 = blockIdx.y * 64, n0 = blockIdx.x * 64;
  const int split = blockIdx.z;
  const int kbeg = split * QCHUNK, kend = kbeg + QCHUNK;
  const int ar = t >> 2, ac = (t & 3) * 8;
  f32x4 acc[2][2];
  for (int i = 0; i < 2; i++)
    for (int j = 0; j < 2; j++) acc[i][j] = (f32x4){0.f, 0.f, 0.f, 0.f};
  const unsigned short* aptr = &A[(m0 + ar) * INPAD + ac];
  const unsigned short* bptr = &Bm[(n0 + ar) * INPAD + ac];
  for (int k0 = kbeg; k0 < kend; k0 += 32) {
    uint4 av = *(const uint4*)(aptr + k0);
    uint4 bv = *(const uint4*)(bptr + k0);
    __syncthreads();
    *(uint4*)&As[ar][ac] = av;
    *(uint4*)&Bs[ar][ac] = bv;
    __syncthreads();
    bf16x8 af[2], bfr[2];
    for (int i = 0; i < 2; i++) {
      af[i]  = *(const bf16x8*)&As[wm * 32 + i * 16 + lo][quad * 8];
      bfr[i] = *(const bf16x8*)&Bs[wn * 32 + i * 16 + lo][quad * 8];
    }
    for (int mi = 0; mi < 2; mi++)
      for (int ni = 0; ni < 2; ni++)
        acc[mi][ni] = __builtin_amdgcn_mfma_f32_16x16x32_bf16(af[mi], bfr[ni], acc[mi][ni], 0, 0, 0);
  }
  float* outp = qp + (size_t)split * BATCH * HID;
  for (int mi = 0; mi < 2; mi++)
    for (int ni = 0; ni < 2; ni++)
      for (int r = 0; r < 4; r++) {
        int row = m0 + wm * 32 + mi * 16 + quad * 4 + r;   // b
        int col = n0 + wn * 32 + ni * 16 + lo;             // h
        outp[row * HID + col] = acc[mi][ni][r];            // 4B/lane, 16-lane contig
      }
}

// qhat[b][h] = bf16(sum_s qp * beta/||q_b||); packed uint stores; zero l
__global__ __launch_bounds__(384) void k_qhat(const float* __restrict__ qp,
                                              const int* __restrict__ beta,
                                              unsigned* __restrict__ qhat,
                                              float* __restrict__ l) {
  int b = blockIdx.x, t = threadIdx.x;   // 384 threads: pair t = cols 2t,2t+1
  float x = 0.f, y = 0.f;
  for (int s = 0; s < QSPLITS; s++) {
    float2 p = *(const float2*)&qp[(size_t)s * BATCH * HID + b * HID + 2 * t];
    x += p.x; y += p.y;
  }
  float ss = x * x + y * y;
  for (int m = 1; m < 64; m <<= 1) ss += __shfl_xor(ss, m, 64);
  __shared__ float sacc[6];
  if ((t & 63) == 0) sacc[t >> 6] = ss;
  __syncthreads();
  float tot = sacc[0] + sacc[1] + sacc[2] + sacc[3] + sacc[4] + sacc[5];
  // ref denom is (qn*en + 1e-8); qn*en ~ 1.3e3 so eps is rel ~7e-12: folded out.
  float scale = (float)beta[0] / sqrtf(tot);
  qhat[b * (HID / 2) + t] = pack2(x * scale, y * scale);
  if (t == 0) l[b] = 0.f;
}

// ---------------- GEMM1 (fused wprep): E = exp((qhat @ bf16(W)^T) * inv_en) ----
// grid (2 m-blocks, 393 n-blocks). B-staging reads W fp32, converts to bf16
// in-register, stages Bs, accumulates per-row squared sums (inv_l computed
// in-block after the k-loop: each block sees all 768 cols of its 128 vocab
// rows). m-block 0 also streams the bf16 values to Wb global for gemm2
// (uint4/thread; 64B-contiguous per 4-lane group; L2 write-combines the rest).
// Rows >= VOCAB clamp their loads to row VOCAB-1 (garbage ok: epilogue zeroes
// E there, and gemm2 multiplies Wb's garbage rows by E=0).
// R9 reg-prefetch pipeline retained.

__global__ __launch_bounds__(256) void k_gemm1(const unsigned short* __restrict__ A,   // qhat [256][768]
                                               const float* __restrict__ Wf,           // W [50257][768] f32
                                               unsigned* __restrict__ Wb,              // out [VPAD][384] uints
                                               unsigned short* __restrict__ E,         // [256][VPAD]
                                               float* __restrict__ l) {
  __shared__ unsigned short As[128][32];
  __shared__ unsigned short Bs[128][32];
  __shared__ unsigned short Et[128][128];   // staged output tile (32 KB)
  __shared__ float rowsum[128];
  __shared__ float inv_l[128];
  const int t = threadIdx.x;
  const int lane = t & 63, wave = t >> 6;
  const int wm = wave >> 1, wn = wave & 1;
  const int quad = lane >> 4, lo = lane & 15;
  const int m0 = blockIdx.x * 128, n0 = blockIdx.y * 128;
  const int ar = t >> 2, ac = (t & 3) * 8;
  const bool bx0 = (blockIdx.x == 0);
  if (t < 128) rowsum[t] = 0.f;
  f32x4 acc[4][4];
  for (int i = 0; i < 4; i++)
    for (int j = 0; j < 4; j++) acc[i][j] = (f32x4){0.f, 0.f, 0.f, 0.f};
  const unsigned short* aptr  = &A[(m0 + ar) * HID + ac];
  const unsigned short* aptr2 = &A[(m0 + ar + 64) * HID + ac];
  const int vr0 = n0 + ar, vr1 = n0 + ar + 64;           // vocab rows (may pad)
  const int vc0 = (vr0 < VOCAB) ? vr0 : (VOCAB - 1);     // clamped loads
  const int vc1 = (vr1 < VOCAB) ? vr1 : (VOCAB - 1);
  const float* wp0 = &Wf[(size_t)vc0 * HID + ac];
  const float* wp1 = &Wf[(size_t)vc1 * HID + ac];
  float ss0 = 0.f, ss1 = 0.f;
  // prologue: loads for k0=0
  uint4 av0  = *(const uint4*)(aptr);
  uint4 av1  = *(const uint4*)(aptr2);
  float4 b0a = *(const float4*)(wp0);
  float4 b0b = *(const float4*)(wp0 + 4);
  float4 b1a = *(const float4*)(wp1);
  float4 b1b = *(const float4*)(wp1 + 4);
  for (int k0 = 0; k0 < HID; k0 += 32) {
    __syncthreads();
    *(uint4*)&As[ar][ac]      = av0;
    *(uint4*)&As[ar + 64][ac] = av1;
    uint4 w0 = (uint4){pack2(b0a.x, b0a.y), pack2(b0a.z, b0a.w),
                       pack2(b0b.x, b0b.y), pack2(b0b.z, b0b.w)};
    uint4 w1 = (uint4){pack2(b1a.x, b1a.y), pack2(b1a.z, b1a.w),
                       pack2(b1b.x, b1b.y), pack2(b1b.z, b1b.w)};
    *(uint4*)&Bs[ar][ac]      = w0;        // coverage: rows 0..127 x k 0..31
    *(uint4*)&Bs[ar + 64][ac] = w1;
    ss0 += b0a.x * b0a.x + b0a.y * b0a.y + b0a.z * b0a.z + b0a.w * b0a.w
         + b0b.x * b0b.x + b0b.y * b0b.y + b0b.z * b0b.z + b0b.w * b0b.w;
    ss1 += b1a.x * b1a.x + b1a.y * b1a.y + b1a.z * b1a.z + b1a.w * b1a.w
         + b1b.x * b1b.x + b1b.y * b1b.y + b1b.z * b1b.z + b1b.w * b1b.w;
    if (bx0) {                             // Wb written once across the grid
      *(uint4*)&Wb[(size_t)vr0 * (HID / 2) + (k0 + ac) / 2] = w0;
      *(uint4*)&Wb[(size_t)vr1 * (HID / 2) + (k0 + ac) / 2] = w1;
    }
    __syncthreads();
    // prefetch next k-step (dummy reload of k=0 on last iter, discarded)
    const int kn = (k0 + 32 < HID) ? k0 + 32 : 0;
    av0 = *(const uint4*)(aptr + kn);
    av1 = *(const uint4*)(aptr2 + kn);
    b0a = *(const float4*)(wp0 + kn);
    b0b = *(const float4*)(wp0 + kn + 4);
    b1a = *(const float4*)(wp1 + kn);
    b1b = *(const float4*)(wp1 + kn + 4);
    __builtin_amdgcn_sched_barrier(0);   // loads issue before the MFMA cluster
    bf16x8 af[4], bfr[4];
    for (int i = 0; i < 4; i++) {
      af[i]  = *(const bf16x8*)&As[wm * 64 + i * 16 + lo][quad * 8];
      bfr[i] = *(const bf16x8*)&Bs[wn * 64 + i * 16 + lo][quad * 8];
    }
    for (int mi = 0; mi < 4; mi++)
      for (int ni = 0; ni < 4; ni++)
        acc[mi][ni] = __builtin_amdgcn_mfma_f32_16x16x32_bf16(af[mi], bfr[ni], acc[mi][ni], 0, 0, 0);
  }
  // finish inv_l: threads 4ar..4ar+3 (consecutive lanes) hold disjoint col sums
  ss0 += __shfl_xor(ss0, 1, 64);
  ss0 += __shfl_xor(ss0, 2, 64);
  ss1 += __shfl_xor(ss1, 1, 64);
  ss1 += __shfl_xor(ss1, 2, 64);
  if ((t & 3) == 0) {
    inv_l[ar]      = (vr0 < VOCAB) ? (1.f / sqrtf(ss0)) : 0.f;
    inv_l[ar + 64] = (vr1 < VOCAB) ? (1.f / sqrtf(ss1)) : 0.f;
  }
  __syncthreads();
  // epilogue: E = exp(acc * inv_l) into LDS tile + rowsum reduce
  for (int mi = 0; mi < 4; mi++)
    for (int ni = 0; ni < 4; ni++) {
      int cl = wn * 64 + ni * 16 + lo;
      int vg = n0 + cl;
      bool valid = (vg < VOCAB);
      float ie = inv_l[cl];
      for (int r = 0; r < 4; r++) {
        int row = wm * 64 + mi * 16 + quad * 4 + r;
        float e = valid ? __expf(acc[mi][ni][r] * ie) : 0.f;   // logits in [-8,8]
        Et[row][cl] = f2bf(e);
        float s = e;
        s += __shfl_xor(s, 1, 64);
        s += __shfl_xor(s, 2, 64);
        s += __shfl_xor(s, 4, 64);
        s += __shfl_xor(s, 8, 64);
        if (lo == 0) atomicAdd(&rowsum[row], s);
      }
    }
  __syncthreads();
  // cooperative full-line writes: 128 rows x 256B: 2048 uint4 = 8 passes x 256
  for (int i = 0; i < 8; i++) {
    int idx = t + i * 256;
    int row = idx >> 4, j = idx & 15;
    *(uint4*)&E[(size_t)(m0 + row) * VPAD + n0 + j * 8] = *(const uint4*)&Et[row][j * 8];
  }
  if (t < 128) atomicAdd(&l[m0 + t], rowsum[t]);
}

// ---------------- GEMM2 (K-split): Pp[s][h][b] = partial sum_v Wb[v][h]*E[b][v] ----
// R7 shape (3D grid, 128x128 tile) + R9 reg-prefetch pipeline.
// A-tile transposed during staging from row-major Wb: thread t reads Wb row
// v=t>>3, h-chunks (t&7),(t&7)+8 as uint4 (coalesced 128B/row/wave), writes 16
// transposed ds_write_u16 into As[128][34] (pitch 17 dwords: write banks
// ~4-way, hidden under MFMA; frag reads 4xb32 ~2-way).

__global__ __launch_bounds__(256) void k_gemm2(const unsigned short* __restrict__ Wb,  // [VPAD][768]
                                               const unsigned short* __restrict__ Bm,  // E [256][VPAD]
                                               float* __restrict__ Pp) {
  __shared__ unsigned short As[128][34];   // [m=h][k=v], padded pitch
  __shared__ unsigned short Bs[128][32];
  const int t = threadIdx.x;
  const int lane = t & 63, wave = t >> 6;
  const int wm = wave >> 1, wn = wave & 1;
  const int quad = lane >> 4, lo = lane & 15;
  const int m0 = blockIdx.x * 128, n0 = blockIdx.y * 128;   // m = h, n = b
  const int split = blockIdx.z;
  const int kbeg = split * CHUNK;
  const int kend = (kbeg + CHUNK < VPAD) ? kbeg + CHUNK : VPAD;
  const int sv = t >> 3, shc = t & 7;      // A-staging: Wb row sv, h-chunks shc/shc+8
  const int ar = t >> 2, ac = (t & 3) * 8; // B-staging
  f32x4 acc[4][4];
  for (int i = 0; i < 4; i++)
    for (int j = 0; j < 4; j++) acc[i][j] = (f32x4){0.f, 0.f, 0.f, 0.f};
  const unsigned short* bptr  = &Bm[(size_t)(n0 + ar) * VPAD + ac];
  const unsigned short* bptr2 = &Bm[(size_t)(n0 + ar + 64) * VPAD + ac];
  // prologue: loads for k0=kbeg
  uint4 a0  = *(const uint4*)&Wb[(size_t)(kbeg + sv) * HID + m0 + shc * 8];
  uint4 a1  = *(const uint4*)&Wb[(size_t)(kbeg + sv) * HID + m0 + (shc + 8) * 8];
  uint4 bv0 = *(const uint4*)(bptr + kbeg);
  uint4 bv1 = *(const uint4*)(bptr2 + kbeg);
  for (int k0 = kbeg; k0 < kend; k0 += 32) {
    __syncthreads();
    {
      const unsigned short* e0 = (const unsigned short*)&a0;
      const unsigned short* e1 = (const unsigned short*)&a1;
#pragma unroll
      for (int j = 0; j < 8; j++) {
        As[shc * 8 + j][sv]       = e0[j];   // coverage: m 0..63 x v 0..31
        As[(shc + 8) * 8 + j][sv] = e1[j];   // coverage: m 64..127 x v 0..31
      }
    }
    *(uint4*)&Bs[ar][ac]      = bv0;         // coverage: n 0..127 x k 0..31
    *(uint4*)&Bs[ar + 64][ac] = bv1;
    __syncthreads();
    // prefetch next k-step (clamped dummy reload on last iter, discarded)
    const int kn = (k0 + 32 < kend) ? k0 + 32 : kbeg;
    a0  = *(const uint4*)&Wb[(size_t)(kn + sv) * HID + m0 + shc * 8];
    a1  = *(const uint4*)&Wb[(size_t)(kn + sv) * HID + m0 + (shc + 8) * 8];
    bv0 = *(const uint4*)(bptr + kn);
    bv1 = *(const uint4*)(bptr2 + kn);
    __builtin_amdgcn_sched_barrier(0);   // loads issue before the MFMA cluster
    bf16x8 af[4], bfr[4];
#pragma unroll
    for (int i = 0; i < 4; i++) {
      const unsigned* rp = (const unsigned*)&As[wm * 64 + i * 16 + lo][quad * 8];
      uint4 u; u.x = rp[0]; u.y = rp[1]; u.z = rp[2]; u.w = rp[3];   // 4x b32
      af[i]  = *(const bf16x8*)&u;
      bfr[i] = *(const bf16x8*)&Bs[wn * 64 + i * 16 + lo][quad * 8];
    }
    for (int mi = 0; mi < 4; mi++)
      for (int ni = 0; ni < 4; ni++)
        acc[mi][ni] = __builtin_amdgcn_mfma_f32_16x16x32_bf16(af[mi], bfr[ni], acc[mi][ni], 0, 0, 0);
  }
  float* outp = Pp + (size_t)split * HID * BATCH;
  for (int mi = 0; mi < 4; mi++)
    for (int ni = 0; ni < 4; ni++)
      for (int r = 0; r < 4; r++) {
        int h = m0 + wm * 64 + mi * 16 + quad * 4 + r;
        int b = n0 + wn * 64 + ni * 16 + lo;
        outp[h * BATCH + b] = acc[mi][ni][r];   // 4B/lane, 16-lane contig
      }
}

// out[b][h] = (sum_s Pp[s][h][b]) / l[b]
__global__ __launch_bounds__(256) void k_reduce(const float* __restrict__ Pp,
                                                const float* __restrict__ l,
                                                float* __restrict__ out) {
  int idx = blockIdx.x * 256 + threadIdx.x;   // h*256 + b
  int h = idx >> 8, b = idx & 255;
  float s = 0.f;
  for (int i = 0; i < SPLITS; i++) s += Pp[(size_t)i * (HID * BATCH) + idx];
  out[b * HID + h] = s / l[b];
}

// ---------------- launch ----------------

extern "C" void kernel_launch(void* const* d_in, const int* in_sizes, int n_in,
                              void* d_out, int out_size, void* d_ws, size_t ws_size,
                              hipStream_t stream) {
  const float* obs  = (const float*)d_in[0];   // [256,3,84,84]
  const float* W    = (const float*)d_in[1];   // [50257,768]
  const float* proj = (const float*)d_in[2];   // [768,7056]
  const int* beta   = (const int*)d_in[3];     // scalar int
  float* out = (float*)d_out;                  // [256,768] f32

  char* ws = (char*)d_ws;
  size_t off = 0;
  auto alloc = [&](size_t bytes) -> void* {
    void* p = ws + off;
    off = (off + bytes + 255) & ~(size_t)255;
    return p;
  };
  unsigned short* Wb    = (unsigned short*)alloc((size_t)VPAD * HID * 2);   // 77.3 MB
  unsigned short* obsb  = (unsigned short*)alloc((size_t)BATCH * INPAD * 2);
  unsigned short* projb = (unsigned short*)alloc((size_t)HID * INPAD * 2);
  unsigned short* qhat  = (unsigned short*)alloc((size_t)BATCH * HID * 2);
  float* l              = (float*)alloc((size_t)BATCH * 4);
  unsigned short* E     = (unsigned short*)alloc((size_t)BATCH * VPAD * 2);  // 25.8 MB
  float* Pp             = (float*)alloc((size_t)SPLITS * BATCH * HID * 4);   // 25.2 MB
  float* qp             = Pp;   // alias: qp (13.4 MB) dead before gemm2 writes Pp
  (void)ws_size; (void)in_sizes; (void)n_in; (void)out_size;                 // ~129 MB total

  k_obs  <<<dim3(BATCH), dim3(256), 0, stream>>>(obs, (unsigned*)obsb);
  k_proj <<<dim3(HID), dim3(256), 0, stream>>>(proj, (unsigned*)projb);
  k_qgemm<<<dim3(HID / 64, BATCH / 64, QSPLITS), dim3(256), 0, stream>>>(obsb, projb, qp);
  k_qhat <<<dim3(BATCH), dim3(384), 0, stream>>>(qp, beta, (unsigned*)qhat, l);
  k_gemm1<<<dim3(BATCH / 128, VPAD / 128), dim3(256), 0, stream>>>(qhat, W, (unsigned*)Wb, E, l);
  k_gemm2<<<dim3(HID / 128, BATCH / 128, SPLITS), dim3(256), 0, stream>>>(Wb, E, Pp);
  k_reduce<<<dim3(BATCH * HID / 256), dim3(256), 0, stream>>>(Pp, l, out);
}